// Round 9
// baseline (128.797 us; speedup 1.0000x reference)
//
#include <hip/hip_runtime.h>
#include <hip/hip_bf16.h>

typedef unsigned short u16;
typedef unsigned int u32;
typedef __attribute__((ext_vector_type(8))) short bf16x8;   // 8 bf16 = 4 VGPR
typedef __attribute__((ext_vector_type(16))) float f32x16;  // 32x32 C/D frag
typedef _Float16 h16x2 __attribute__((ext_vector_type(2)));

static __device__ __forceinline__ u16 f2bf(float f) {
    __hip_bfloat16 b = __float2bfloat16(f);   // RNE
    return *(u16*)&b;
}

// ---------------------------------------------------------------------------
// Kernel 0: build W1's MFMA fragment table ONCE (node-independent).
// wtab flat index = ((ct*4 + ks)*64 + lane)*8 + j  holds (bf16)
//   Wcat[k = ks*16 + (lane>>5)*8 + j][c = ct*32 + (lane&31)]
// where Wcat[k][c] = c<64 ? W1[k][c] : W1[64+k][c-64].
// This table serves as the MFMA *A* operand for the swapped product
// D = Wcat^T-tile . z-tile (A and B fragments share the same indexing).
// ---------------------------------------------------------------------------
__global__ __launch_bounds__(256) void build_wfrag(
    const float* __restrict__ W1, u16* __restrict__ wtab)
{
    const int flat = blockIdx.x * 256 + threadIdx.x;
    if (flat >= 8192) return;
    const int j    = flat & 7;
    const int lane = (flat >> 3) & 63;
    const int ks   = (flat >> 9) & 3;
    const int ct   = flat >> 11;
    const int k = ks * 16 + (lane >> 5) * 8 + j;
    const int c = ct * 32 + (lane & 31);
    const float v = (c < 64) ? W1[(size_t)k * 64 + c]
                             : W1[(size_t)(64 + k) * 64 + (c - 64)];
    wtab[flat] = f2bf(v);
}

// ---------------------------------------------------------------------------
// Kernel A (MFMA, swapped operands): computes D[c][node] so that each lane
// owns ONE node's full pq row.
//   pq[n][c]:  c<64 (P): b1[c] + sum_k z[n][k]*W1[k][c]
//              c>=64(Q):          sum_k z[n][k]*W1[64+k][c-64]
// mfma_f32_32x32x16_bf16 with A = W-fragment (m=c), B = z-fragment (n=node):
//   D col = lane&31 = node-in-tile, row = (reg&3)+8*(reg>>2)+4*(lane>>5) = c.
// reg&3 gives 4 CONSECUTIVE c -> pack via v_cvt_pkrtz and store 8 B chunks:
// 16 dwordx2 stores/thread vs 64 scattered 2-B stores in R7.
// ---------------------------------------------------------------------------
__global__ __launch_bounds__(256) void node_mfma(
    const float* __restrict__ z, const u16* __restrict__ wtab,
    const float* __restrict__ b1, u16* __restrict__ pq, int nNodes)
{
    const int lane   = threadIdx.x & 63;
    const int wave   = threadIdx.x >> 6;
    const int l31    = lane & 31;
    const int half   = lane >> 5;
    const int nodeBase = (blockIdx.x * 4 + wave) * 32;
    if (nodeBase >= nNodes) return;

    // ---- W fragments (A operand): coalesced loads from the table
    const bf16x8* wt = (const bf16x8*)wtab;
    bf16x8 Wf[4][4];
#pragma unroll
    for (int ct = 0; ct < 4; ++ct)
#pragma unroll
        for (int ks = 0; ks < 4; ++ks)
            Wf[ct][ks] = wt[(ct * 4 + ks) * 64 + lane];

    // ---- z fragments (B operand): Zf[ks][j] = z[nodeBase+l31][ks*16+half*8+j]
    int zrowi = nodeBase + l31;
    if (zrowi > nNodes - 1) zrowi = nNodes - 1;       // clamp (safe redundant)
    const float* zrow = z + (size_t)zrowi * 64;
    bf16x8 Zf[4];
#pragma unroll
    for (int ks = 0; ks < 4; ++ks) {
        const float4 v0 = *(const float4*)(zrow + ks * 16 + half * 8);
        const float4 v1 = *(const float4*)(zrow + ks * 16 + half * 8 + 4);
        Zf[ks][0] = (short)f2bf(v0.x); Zf[ks][1] = (short)f2bf(v0.y);
        Zf[ks][2] = (short)f2bf(v0.z); Zf[ks][3] = (short)f2bf(v0.w);
        Zf[ks][4] = (short)f2bf(v1.x); Zf[ks][5] = (short)f2bf(v1.y);
        Zf[ks][6] = (short)f2bf(v1.z); Zf[ks][7] = (short)f2bf(v1.w);
    }

    // ---- MFMA accumulate (A = W, B = z  ->  D = D^T of the R7 version)
    f32x16 acc[4];
#pragma unroll
    for (int ct = 0; ct < 4; ++ct) acc[ct] = (f32x16)(0.0f);
#pragma unroll
    for (int ks = 0; ks < 4; ++ks)
#pragma unroll
        for (int ct = 0; ct < 4; ++ct)
            acc[ct] = __builtin_amdgcn_mfma_f32_32x32x16_bf16(
                Wf[ct][ks], Zf[ks], acc[ct], 0, 0, 0);

    // ---- epilogue: lane l31 owns node nodeBase+l31 entirely.
    // c = ct*32 + 8*g + 4*half + r  for acc[ct][4*g + r], r = 0..3.
    const int node = nodeBase + l31;
    if (node < nNodes) {
        u16* prow = pq + (size_t)node * 128;
#pragma unroll
        for (int ct = 0; ct < 4; ++ct) {
#pragma unroll
            for (int g = 0; g < 4; ++g) {
                const int c0 = ct * 32 + 8 * g + 4 * half;
                float v0 = acc[ct][4 * g + 0];
                float v1 = acc[ct][4 * g + 1];
                float v2 = acc[ct][4 * g + 2];
                float v3 = acc[ct][4 * g + 3];
                if (ct < 2) {   // P half gets the bias (c0 < 64 always here)
                    v0 += b1[c0 + 0]; v1 += b1[c0 + 1];
                    v2 += b1[c0 + 2]; v3 += b1[c0 + 3];
                }
                uint2 st;
                st.x = __builtin_bit_cast(u32, __builtin_amdgcn_cvt_pkrtz(v0, v1));
                st.y = __builtin_bit_cast(u32, __builtin_amdgcn_cvt_pkrtz(v2, v3));
                *(uint2*)(prow + c0) = st;
            }
        }
    }
}

// ---------------------------------------------------------------------------
// Kernel B: edge MLP tail, 8 lanes per edge, packed fp16 math (unchanged —
// gather-bound per R6; VALU trim bought only ~2 us).
//   out[e] = b2 + sum_h W2[h] * relu(P[i][h] + Q[j][h])
// ---------------------------------------------------------------------------
__global__ __launch_bounds__(256) void edge_mlp(
    const int* __restrict__ e0, const int* __restrict__ e1,
    const u16* __restrict__ pq, const float* __restrict__ W2,
    const float* __restrict__ b2, float* __restrict__ out, int E)
{
    const int gid = blockIdx.x * 256 + threadIdx.x;
    const int e   = gid >> 3;
    const int sub = gid & 7;
    if (e >= E) return;

    const int i = e0[e];
    const int j = e1[e];

    const uint4 p = ((const uint4*)(pq + (size_t)i * 128))[sub];
    const uint4 q = ((const uint4*)(pq + (size_t)j * 128 + 64))[sub];

    const float4 wa = ((const float4*)W2)[2 * sub];
    const float4 wb = ((const float4*)W2)[2 * sub + 1];

    const u32 pw[4] = {p.x, p.y, p.z, p.w};
    const u32 qw[4] = {q.x, q.y, q.z, q.w};

    h16x2 w2h[4];
    w2h[0] = (h16x2){(_Float16)wa.x, (_Float16)wa.y};
    w2h[1] = (h16x2){(_Float16)wa.z, (_Float16)wa.w};
    w2h[2] = (h16x2){(_Float16)wb.x, (_Float16)wb.y};
    w2h[3] = (h16x2){(_Float16)wb.z, (_Float16)wb.w};
    const h16x2 hzero = (h16x2){(_Float16)0.0f, (_Float16)0.0f};

    float sum = 0.0f;
#pragma unroll
    for (int c = 0; c < 4; ++c) {
        h16x2 pp = __builtin_bit_cast(h16x2, pw[c]);
        h16x2 qq = __builtin_bit_cast(h16x2, qw[c]);
        h16x2 a  = __builtin_elementwise_max(pp + qq, hzero); // pk_add + pk_max
#if __has_builtin(__builtin_amdgcn_fdot2)
        sum = __builtin_amdgcn_fdot2(a, w2h[c], sum, false);
#else
        sum = fmaf((float)a[0], (float)w2h[c][0],
              fmaf((float)a[1], (float)w2h[c][1], sum));
#endif
    }

    sum += __shfl_xor(sum, 1);
    sum += __shfl_xor(sum, 2);
    sum += __shfl_xor(sum, 4);

    if (sub == 0) out[e] = sum + b2[0];
}

// ---------------------------------------------------------------------------
extern "C" void kernel_launch(void* const* d_in, const int* in_sizes, int n_in,
                              void* d_out, int out_size, void* d_ws, size_t ws_size,
                              hipStream_t stream) {
    const float* z  = (const float*)d_in[0];
    const int*   eg = (const int*)d_in[1];
    const float* W1 = (const float*)d_in[2];
    const float* b1 = (const float*)d_in[3];
    const float* W2 = (const float*)d_in[4];
    const float* b2 = (const float*)d_in[5];
    float* out = (float*)d_out;

    const int nNodes = in_sizes[0] / 64;   // 100000
    const int E      = in_sizes[1] / 2;    // 1000000

    u16* wtab = (u16*)d_ws;                        // 16 KB fragment table
    u16* pq   = (u16*)d_ws + 16384;                // nNodes*128*2 = 25.6 MB

    build_wfrag<<<dim3(32), dim3(256), 0, stream>>>(W1, wtab);

    dim3 gA((nNodes + 127) / 128);         // 4 waves x 32 nodes per block
    node_mfma<<<gA, dim3(256), 0, stream>>>(z, wtab, b1, pq, nNodes);

    long long tB = (long long)E * 8;       // 8 threads per edge
    dim3 gB((unsigned)((tB + 255) / 256));
    edge_mlp<<<gB, dim3(256), 0, stream>>>(eg, eg + E, pq, W2, b2, out, E);
}